// Round 1
// 679.896 us; speedup vs baseline: 1.1238x; 1.1238x over previous
//
#include <hip/hip_runtime.h>
#include <cstddef>

// SpectralConv2d (FNO): B=16, Cin=Cout=64, H=W=256, modes 20x20.
//   A: W-DFT   x[B,C,H,256]  -> X1[B,C,H,20]  (c64)   [d_out scratch]
//   B: H-DFT   X1            -> X2[B,C,40,20]          [ws]
//   M: mix     X2 (x) w1/w2  -> Z [B,Co,40,20]         [ws]
//   CD: inv-H + inv-rfft-W fused: Z -> out[B,Co,256,256]
// R4: A rewritten with real-input fold (u=x[w]+x[256-w], d=x[w]-x[256-w]:
//     halves FMAs + loop) and 2 kx per thread (halves LDS read issue);
//     XOR-swizzled LDS quads keep reads conflict-free.
//     CD phase 3 rewritten with out[w]/out[256-w] symmetry (P/Q split) and
//     k-pair float4 reads (4x fewer LDS issues); w=0/128 columns emitted
//     directly from phase 2.

constexpr float KTH = 6.28318530717958647692f / 256.0f; // 2*pi/256

// ---------------- Kernel A: partial DFT along W ----------------
// grid 2048 (128 rows/block), block 320 = 32 slots x 10 kx-pairs.
// Staged per 32-w chunk: u'[j]=x[j+1]+x[255-j], d'[j]=x[j+1]-x[255-j]
// (j=0..127; u'[127]=x[128], d'[127]=0; x[0] added at the end).
// re[k] = x0 + sum_j u'[j] cos(k(j+1)th); im[k] = -sum_j d'[j] sin(k(j+1)th).
// LDS row layout: u quads 0..7 | d quads 8..15, quad col ^= (row>>2)&3
// (swizzle keeps the 6.4-distinct-row wave reads <=2-way = free).
__global__ __launch_bounds__(320) void dft_w_kernel(const float* __restrict__ x,
                                                    float2* __restrict__ X1) {
  __shared__ float uds[128 * 68];  // 34.8 KB: per row 32 u | 32 d | 4 pad
  __shared__ float xs0[128];
  const int tid = threadIdx.x;
  const int sl = tid / 10;         // slot 0..31 (4 rows each)
  const int kp = tid - sl * 10;    // kx pair 0..9 -> kx = 2kp, 2kp+1
  const size_t row0 = (size_t)blockIdx.x * 128;
  const float* xb = x + row0 * 256;

  float cr0, sr0, cr1, sr1;
  __sincosf((float)(2 * kp) * KTH, &sr0, &cr0);
  __sincosf((float)(2 * kp + 1) * KTH, &sr1, &cr1);

  float re[4][2] = {};
  float im[4][2] = {};

  const int swc = sl & 3;
  const float* ub = uds + sl * 4 * 68;

  for (int c = 0; c < 4; ++c) {
    __syncthreads();  // previous chunk fully consumed
    if (tid < 256) {  // stage: 128 rows x 2 halves of 16 cols
      const int row = tid >> 1;
      const int hf = tid & 1;
      const int base = c * 32 + hf * 16;  // j base
      const float* xr = xb + (size_t)row * 256;
      // fwd covers x[base .. base+19] (need x[base+1 .. base+16])
      float4 fq0 = *(const float4*)(xr + base);
      float4 fq1 = *(const float4*)(xr + base + 4);
      float4 fq2 = *(const float4*)(xr + base + 8);
      float4 fq3 = *(const float4*)(xr + base + 12);
      float4 fq4 = *(const float4*)(xr + base + 16);
      // mirror covers x[240-base .. 255-base] = x[255-j], j in [base, base+16)
      const float* xm = xr + (240 - base);
      float4 mq0 = *(const float4*)(xm);
      float4 mq1 = *(const float4*)(xm + 4);
      float4 mq2 = *(const float4*)(xm + 8);
      float4 mq3 = *(const float4*)(xm + 12);
      if (c == 0 && hf == 0) xs0[row] = fq0.x;  // x[0]
      float* urow = uds + row * 68;
      const int sw = (row >> 2) & 3;
#define STAGE_Q(q, fa, fb, m)                                         \
      {                                                               \
        float4 u, d;                                                  \
        u.x = fa.y + m.w; d.x = fa.y - m.w;                           \
        u.y = fa.z + m.z; d.y = fa.z - m.z;                           \
        u.z = fa.w + m.y; d.z = fa.w - m.y;                           \
        u.w = fb.x + m.x; d.w = fb.x - m.x;                           \
        if (c == 3 && hf == 1 && (q) == 3) u.w *= 0.5f; /* j=127 */   \
        int col = (((hf * 4 + (q)) ^ sw) * 4);                        \
        *(float4*)(urow + col) = u;                                   \
        *(float4*)(urow + 32 + col) = d;                              \
      }
      STAGE_Q(0, fq0, fq1, mq3)
      STAGE_Q(1, fq1, fq2, mq2)
      STAGE_Q(2, fq2, fq3, mq1)
      STAGE_Q(3, fq3, fq4, mq0)
#undef STAGE_Q
    }
    __syncthreads();

    for (int g = 0; g < 2; ++g) {
      const int w1 = c * 32 + g * 16 + 1;  // w of first element in group
      float c0, s0, c1, s1;
      { int m = (2 * kp * w1) & 255;       __sincosf((float)m * KTH, &s0, &c0); }
      { int m = ((2 * kp + 1) * w1) & 255; __sincosf((float)m * KTH, &s1, &c1); }
#pragma unroll
      for (int q = 0; q < 4; ++q) {
        const int col = (((g * 4 + q) ^ swc) * 4);
        float4 u0 = *(const float4*)(ub + col);
        float4 d0 = *(const float4*)(ub + 32 + col);
        float4 u1 = *(const float4*)(ub + 68 + col);
        float4 d1 = *(const float4*)(ub + 68 + 32 + col);
        float4 u2 = *(const float4*)(ub + 136 + col);
        float4 d2 = *(const float4*)(ub + 136 + 32 + col);
        float4 u3 = *(const float4*)(ub + 204 + col);
        float4 d3 = *(const float4*)(ub + 204 + 32 + col);
#define DSTEP(e)                                                      \
        {                                                             \
          re[0][0] = fmaf(u0.e, c0, re[0][0]);                        \
          im[0][0] = fmaf(d0.e, s0, im[0][0]);                        \
          re[1][0] = fmaf(u1.e, c0, re[1][0]);                        \
          im[1][0] = fmaf(d1.e, s0, im[1][0]);                        \
          re[2][0] = fmaf(u2.e, c0, re[2][0]);                        \
          im[2][0] = fmaf(d2.e, s0, im[2][0]);                        \
          re[3][0] = fmaf(u3.e, c0, re[3][0]);                        \
          im[3][0] = fmaf(d3.e, s0, im[3][0]);                        \
          re[0][1] = fmaf(u0.e, c1, re[0][1]);                        \
          im[0][1] = fmaf(d0.e, s1, im[0][1]);                        \
          re[1][1] = fmaf(u1.e, c1, re[1][1]);                        \
          im[1][1] = fmaf(d1.e, s1, im[1][1]);                        \
          re[2][1] = fmaf(u2.e, c1, re[2][1]);                        \
          im[2][1] = fmaf(d2.e, s1, im[2][1]);                        \
          re[3][1] = fmaf(u3.e, c1, re[3][1]);                        \
          im[3][1] = fmaf(d3.e, s1, im[3][1]);                        \
          float cn0 = c0 * cr0 - s0 * sr0;                            \
          s0 = fmaf(c0, sr0, s0 * cr0);                               \
          c0 = cn0;                                                   \
          float cn1 = c1 * cr1 - s1 * sr1;                            \
          s1 = fmaf(c1, sr1, s1 * cr1);                               \
          c1 = cn1;                                                   \
        }
        DSTEP(x) DSTEP(y) DSTEP(z) DSTEP(w)
#undef DSTEP
      }
    }
  }

#pragma unroll
  for (int r = 0; r < 4; ++r) {
    float x0v = xs0[sl * 4 + r];  // staged chunk 0, still valid
    size_t ob = (row0 + (size_t)(sl * 4 + r)) * 20 + (size_t)(kp * 2);
    float4 o;
    o.x = re[r][0] + x0v;
    o.y = -im[r][0];
    o.z = re[r][1] + x0v;
    o.w = -im[r][1];
    *(float4*)(X1 + ob) = o;  // (row*20 + 2kp)*8B -> 16B aligned
  }
}

// ---------------- Kernel B: partial DFT along H ----------------
// grid 1024 (=B*Cin), block 448 (7 waves): threads 0..399 = (ky_i 0..39, kx-pair 0..9).
// X1[bc] staged as float4 [h][kxpair] (natural layout, aligned b128 reads).
__global__ __launch_bounds__(448) void dft_h_kernel(const float2* __restrict__ X1,
                                                    float2* __restrict__ X2) {
  __shared__ float4 Xs4[256 * 10];  // 40 KB
  int bc = blockIdx.x;
  const float4* src = (const float4*)(X1 + (size_t)bc * 5120);
  for (int i = threadIdx.x; i < 2560; i += 448) Xs4[i] = src[i];
  __syncthreads();

  int t = threadIdx.x;
  if (t < 400) {
    int ky_i = t / 10;                        // 0..39
    int g    = t % 10;                        // kx pair -> kx = 2g, 2g+1
    int ky = (ky_i < 20) ? ky_i : 216 + ky_i; // 0..19 or 236..255
    float cr, srn;
    __sincosf((float)ky * KTH, &srn, &cr);
    srn = -srn;
    float ar0 = 0.f, ai0 = 0.f, ar1 = 0.f, ai1 = 0.f;
    for (int h0 = 0; h0 < 256; h0 += 16) {
      int m = (ky * h0) & 255;
      float c, s;
      __sincosf((float)m * KTH, &s, &c);
      s = -s;
#pragma unroll
      for (int dh = 0; dh < 16; ++dh) {
        float4 v = Xs4[(h0 + dh) * 10 + g];  // (re0, im0, re1, im1)
        ar0 = fmaf(v.x, c, fmaf(-v.y, s, ar0));
        ai0 = fmaf(v.x, s, fmaf(v.y, c, ai0));
        ar1 = fmaf(v.z, c, fmaf(-v.w, s, ar1));
        ai1 = fmaf(v.z, s, fmaf(v.w, c, ai1));
        float cn = c * cr - s * srn;
        s = fmaf(c, srn, s * cr);
        c = cn;
      }
    }
    size_t ob = (size_t)bc * 800 + (size_t)ky_i * 20 + (size_t)g * 2;
    X2[ob]     = make_float2(ar0, ai0);
    X2[ob + 1] = make_float2(ar1, ai1);
  }
}

// ---------------- Kernel M: complex channel mixing ----------------
// grid 800 (one per (j,kx) mode), block 256. Z[b,o] = sum_i X2[b,i]*W[i,o].
__global__ __launch_bounds__(256) void mix_kernel(const float2* __restrict__ X2,
                                                  const float* __restrict__ w1r,
                                                  const float* __restrict__ w1i,
                                                  const float* __restrict__ w2r,
                                                  const float* __restrict__ w2i,
                                                  float2* __restrict__ Z) {
  __shared__ float2 Xs[16 * 64];  // [b][i]
  __shared__ float Wr[64 * 64];   // [i][o]
  __shared__ float Wi[64 * 64];
  int blk = blockIdx.x;           // j*20+kx
  int j = blk / 20, kx = blk % 20;
  const float* wr; const float* wi; int moff;
  if (j < 20) { wr = w1r; wi = w1i; moff = j * 20 + kx; }
  else        { wr = w2r; wi = w2i; moff = (j - 20) * 20 + kx; }

  for (int io = threadIdx.x; io < 4096; io += 256) {
    Wr[io] = wr[(size_t)io * 400 + moff];
    Wi[io] = wi[(size_t)io * 400 + moff];
  }
  for (int bi = threadIdx.x; bi < 1024; bi += 256) {
    Xs[bi] = X2[(size_t)bi * 800 + blk];
  }
  __syncthreads();

  int b  = threadIdx.x >> 4;         // 0..15
  int o0 = (threadIdx.x & 15) * 4;   // 0,4,...,60
  float zr[4] = {0, 0, 0, 0}, zi[4] = {0, 0, 0, 0};
  for (int i = 0; i < 64; ++i) {
    float2 xv = Xs[b * 64 + i];
#pragma unroll
    for (int q = 0; q < 4; ++q) {
      float wrv = Wr[i * 64 + o0 + q];
      float wiv = Wi[i * 64 + o0 + q];
      zr[q] = fmaf(xv.x, wrv, fmaf(-xv.y, wiv, zr[q]));
      zi[q] = fmaf(xv.x, wiv, fmaf(xv.y, wrv, zi[q]));
    }
  }
#pragma unroll
  for (int q = 0; q < 4; ++q) {
    Z[(size_t)(b * 64 + o0 + q) * 800 + blk] = make_float2(zr[q], zi[q]);
  }
}

// ---------------- Kernel CD: fused inverse-H DFT + inverse rfft-W ----------------
// grid 1024 (=B*Cout), block 256.
// Phase2: thread=h computes Y[h,0..19] -> Ys4 (stride 11 float4, k=0 pre-halved);
//         also emits out[h,0] and out[h,128] directly (cos=+-1, sin=0 columns).
// Phase3: 2 h-groups x 128 w-threads; thread wt computes BOTH out[h,wt] and
//         out[h,256-wt] from shared P=sum Yr cos, Q=sum Yi sin; k read in
//         float4 pairs -> 4x fewer LDS issues than per-(k,w) b64 broadcasts.
__global__ __launch_bounds__(256) void icd_kernel(const float2* __restrict__ Z,
                                                  float* __restrict__ out) {
  __shared__ float2 Zs[800];        // 6.4 KB
  __shared__ float4 Ys4[256 * 11];  // 45 KB: [h][k-pair 0..9], +1 pad
  int bo = blockIdx.x;
  const float2* src = Z + (size_t)bo * 800;
  for (int i = threadIdx.x; i < 800; i += 256) Zs[i] = src[i];
  __syncthreads();

  const float SC = 2.0f / 65536.0f;
  float* outb = out + (size_t)bo * 65536;

  {  // phase 2: inverse H-DFT, thread = h
    int h = threadIdx.x;
    float cr, sr;
    __sincosf((float)h * KTH, &sr, &cr);  // step e^{+2pi i h/256}
    float accr[20], acci[20];
#pragma unroll
    for (int k = 0; k < 20; ++k) { accr[k] = 0.f; acci[k] = 0.f; }
    float c = 1.0f, s = 0.0f;  // j=0 -> ky=0
    for (int j = 0; j < 40; ++j) {
      if (j == 20) {  // jump to ky=236
        int m = (236 * h) & 255;
        __sincosf((float)m * KTH, &s, &c);
      }
#pragma unroll
      for (int k = 0; k < 20; ++k) {
        float2 z = Zs[j * 20 + k];
        accr[k] = fmaf(z.x, c, fmaf(-z.y, s, accr[k]));
        acci[k] = fmaf(z.x, s, fmaf(z.y, c, acci[k]));
      }
      float cn = c * cr - s * sr;
      s = fmaf(c, sr, s * cr);
      c = cn;
    }
    float2* yrow = (float2*)(Ys4 + h * 11);
    yrow[0] = make_float2(0.5f * accr[0], 0.5f * acci[0]);  // DC pre-halved
#pragma unroll
    for (int k = 1; k < 20; ++k) yrow[k] = make_float2(accr[k], acci[k]);
    // direct columns w=0 (sum) and w=128 (alternating sum): sin term is 0
    float sum0 = 0.5f * accr[0];
    float sum128 = 0.5f * accr[0];
#pragma unroll
    for (int k = 1; k < 20; ++k) {
      sum0 += accr[k];
      sum128 += (k & 1) ? -accr[k] : accr[k];
    }
    outb[h * 256] = sum0 * SC;
    outb[h * 256 + 128] = sum128 * SC;
  }
  __syncthreads();

  {  // phase 3: inverse rfft along W with w / 256-w sharing
    int t = threadIdx.x;
    int hg = t >> 7;        // h half
    int wt = t & 127;       // 1..127 active (wt=0 columns done in phase 2)
    if (wt != 0) {
      float cw, sw;
      __sincosf((float)wt * KTH, &sw, &cw);       // e^{+i wt th}
      float c2 = cw * cw - sw * sw;               // e^{+i 2 wt th}
      float s2 = 2.0f * cw * sw;
      int h0e = hg * 128;
      for (int h0 = h0e; h0 < h0e + 128; h0 += 8) {
        float P[8], Q[8];
#pragma unroll
        for (int r = 0; r < 8; ++r) { P[r] = 0.f; Q[r] = 0.f; }
        float c0 = 1.0f, s0 = 0.0f;   // k=0
        float c1 = cw,   s1 = sw;     // k=1
        const float4* yb = Ys4 + h0 * 11;
        for (int p = 0; p < 10; ++p) {
#pragma unroll
          for (int r = 0; r < 8; ++r) {
            float4 y = yb[r * 11 + p];  // (Yr[2p], Yi[2p], Yr[2p+1], Yi[2p+1])
            P[r] = fmaf(y.x, c0, P[r]);
            Q[r] = fmaf(y.y, s0, Q[r]);
            P[r] = fmaf(y.z, c1, P[r]);
            Q[r] = fmaf(y.w, s1, Q[r]);
          }
          float cn0 = c0 * c2 - s0 * s2;
          s0 = fmaf(c0, s2, s0 * c2);
          c0 = cn0;
          float cn1 = c1 * c2 - s1 * s2;
          s1 = fmaf(c1, s2, s1 * c2);
          c1 = cn1;
        }
#pragma unroll
        for (int r = 0; r < 8; ++r) {
          float pv = P[r] * SC, qv = Q[r] * SC;
          outb[(h0 + r) * 256 + wt] = pv - qv;          // out[h, w]
          outb[(h0 + r) * 256 + 256 - wt] = pv + qv;    // out[h, 256-w]
        }
      }
    }
  }
}

extern "C" void kernel_launch(void* const* d_in, const int* in_sizes, int n_in,
                              void* d_out, int out_size, void* d_ws, size_t ws_size,
                              hipStream_t stream) {
  const float* x   = (const float*)d_in[0];
  const float* w1r = (const float*)d_in[1];
  const float* w1i = (const float*)d_in[2];
  const float* w2r = (const float*)d_in[3];
  const float* w2i = (const float*)d_in[4];
  float* out = (float*)d_out;

  // Scratch: X1 (41.9MB c64) in d_out (overwritten later by CD's out writes —
  // X1 consumed by B before M/CD run). ws: X2 | Z (float2 units).
  float2* X1  = (float2*)d_out;
  float2* wsc = (float2*)d_ws;
  float2* X2  = wsc;
  float2* Zb  = wsc + 819200;  // after X2 (16*64*800 c64)

  dft_w_kernel<<<2048, 320, 0, stream>>>(x, X1);
  dft_h_kernel<<<1024, 448, 0, stream>>>(X1, X2);
  mix_kernel  <<<800, 256, 0, stream>>>(X2, w1r, w1i, w2r, w2i, Zb);
  icd_kernel  <<<1024, 256, 0, stream>>>(Zb, out);
}